// Round 6
// baseline (175.017 us; speedup 1.0000x reference)
//
#include <hip/hip_runtime.h>

typedef __bf16 bf16_t;
typedef __bf16 bf16x8 __attribute__((ext_vector_type(8)));
typedef float f32x4 __attribute__((ext_vector_type(4)));

#define NUM_B 2
#define NUM_H 12
#define SEQ_N 2048
#define DIM_C 768
#define HEAD_D 64
#define BH_CNT (NUM_B * NUM_H)
#define MTOK (NUM_B * SEQ_N)
// qk-scale 1/8 folded with log2(e) so softmax is a bare exp2
#define QSCALE 0.1803368801111137f

#define AS1(p) ((const __attribute__((address_space(1))) void*)(p))
#define AS3(p) ((__attribute__((address_space(3))) void*)(p))

// ---------------------------------------------------------------------------
// f32 -> bf16 bulk convert; final blocks build w = 1 - mask (bf16).
// ---------------------------------------------------------------------------
__global__ __launch_bounds__(256) void cvt_kernel(
    const float* __restrict__ s0, const float* __restrict__ s1,
    const float* __restrict__ s2, const float* __restrict__ msk,
    bf16_t* __restrict__ d0, bf16_t* __restrict__ d1, bf16_t* __restrict__ d2,
    bf16_t* __restrict__ dw, int nb0, int nb1, int nb2) {
  const int blk = blockIdx.x;
  const float* src;
  bf16_t* dst;
  size_t off;
  bool isw = false;
  if (blk < nb0) {
    src = s0; dst = d0; off = (size_t)blk * 2048;
  } else if (blk < nb0 + nb1) {
    src = s1; dst = d1; off = (size_t)(blk - nb0) * 2048;
  } else if (blk < nb0 + nb1 + nb2) {
    src = s2; dst = d2; off = (size_t)(blk - nb0 - nb1) * 2048;
  } else {
    src = msk; dst = dw; off = (size_t)(blk - nb0 - nb1 - nb2) * 2048;
    isw = true;
  }
  const size_t i = off + (size_t)threadIdx.x * 8;
  float4 f0 = *reinterpret_cast<const float4*>(&src[i]);
  float4 f1 = *reinterpret_cast<const float4*>(&src[i + 4]);
  if (isw) {
    f0 = {1.0f - f0.x, 1.0f - f0.y, 1.0f - f0.z, 1.0f - f0.w};
    f1 = {1.0f - f1.x, 1.0f - f1.y, 1.0f - f1.z, 1.0f - f1.w};
  }
  union { ushort4 u; bf16_t h[4]; } p0, p1;
  p0.h[0] = (bf16_t)f0.x; p0.h[1] = (bf16_t)f0.y;
  p0.h[2] = (bf16_t)f0.z; p0.h[3] = (bf16_t)f0.w;
  p1.h[0] = (bf16_t)f1.x; p1.h[1] = (bf16_t)f1.y;
  p1.h[2] = (bf16_t)f1.z; p1.h[3] = (bf16_t)f1.w;
  *reinterpret_cast<ushort4*>(&dst[i]) = p0.u;
  *reinterpret_cast<ushort4*>(&dst[i + 4]) = p1.u;
}

// ---------------------------------------------------------------------------
// QKV GEMM: qkv = x @ qkv_w^T, bf16. 128x128 tile, 4 waves (2x2), wave-tile
// 64x64 (4x4 MFMA 16x16x32). global_load_lds(16B), XOR-swizzled LDS, dbuf.
// Blocks with n0 < 1536 (Q,K): normal MFMA, scatter [B,H,N,D], Q x QSCALE.
// Blocks with n0 >= 1536 (V): SWAPPED MFMA operands -> C tile is transposed
// in-register -> V^T [B,H,D,N] stores are coalesced 32B chunks; x (1-mask).
// ---------------------------------------------------------------------------
__global__ __launch_bounds__(256, 3) void gemm_qkv_kernel(
    const bf16_t* __restrict__ A, const bf16_t* __restrict__ W,
    const float* __restrict__ mask, bf16_t* __restrict__ out) {
  __shared__ __align__(16) bf16_t As[2][128 * 32];
  __shared__ __align__(16) bf16_t Bs[2][128 * 32];

  const int tid = threadIdx.x;
  const int wave = tid >> 6, lane = tid & 63;
  const int quad = lane >> 4, l16 = lane & 15;
  const int m0 = blockIdx.y * 128, n0 = blockIdx.x * 128;
  const int wm = (wave >> 1) * 64, wn = (wave & 1) * 64;
  const bool vmode = (n0 >= 2 * DIM_C);

  f32x4 acc[4][4] = {};

  const int srow = tid >> 2;                            // 0..63, pass1 +64
  const int scol = ((tid & 3) ^ ((tid >> 3) & 3)) * 8;  // swizzled col
  const bf16_t* gA0 = A + (size_t)(m0 + srow) * DIM_C + scol;
  const bf16_t* gA1 = A + (size_t)(m0 + srow + 64) * DIM_C + scol;
  const bf16_t* gB0 = W + (size_t)(n0 + srow) * DIM_C + scol;
  const bf16_t* gB1 = W + (size_t)(n0 + srow + 64) * DIM_C + scol;
  const int lb = wave * 512;

  auto issue = [&](int buf, int k0) {
    __builtin_amdgcn_global_load_lds(AS1(gA0 + k0), AS3(&As[buf][lb]), 16, 0, 0);
    __builtin_amdgcn_global_load_lds(AS1(gA1 + k0), AS3(&As[buf][lb + 2048]), 16, 0, 0);
    __builtin_amdgcn_global_load_lds(AS1(gB0 + k0), AS3(&Bs[buf][lb]), 16, 0, 0);
    __builtin_amdgcn_global_load_lds(AS1(gB1 + k0), AS3(&Bs[buf][lb + 2048]), 16, 0, 0);
  };

  issue(0, 0);
  int cur = 0;
  const int sw = (l16 >> 1) & 3;
  for (int step = 0; step < DIM_C / 32; ++step) {
    __syncthreads();
    if (step + 1 < DIM_C / 32) issue(cur ^ 1, (step + 1) * 32);

    bf16x8 aF[4], bF[4];
#pragma unroll
    for (int mi = 0; mi < 4; ++mi)
      aF[mi] = *reinterpret_cast<const bf16x8*>(
          &As[cur][(wm + mi * 16 + l16) * 32 + ((quad ^ sw) * 8)]);
#pragma unroll
    for (int ni = 0; ni < 4; ++ni)
      bF[ni] = *reinterpret_cast<const bf16x8*>(
          &Bs[cur][(wn + ni * 16 + l16) * 32 + ((quad ^ sw) * 8)]);
    if (vmode) {
#pragma unroll
      for (int mi = 0; mi < 4; ++mi)
#pragma unroll
        for (int ni = 0; ni < 4; ++ni)
          acc[mi][ni] = __builtin_amdgcn_mfma_f32_16x16x32_bf16(
              bF[ni], aF[mi], acc[mi][ni], 0, 0, 0);
    } else {
#pragma unroll
      for (int mi = 0; mi < 4; ++mi)
#pragma unroll
        for (int ni = 0; ni < 4; ++ni)
          acc[mi][ni] = __builtin_amdgcn_mfma_f32_16x16x32_bf16(
              aF[mi], bF[ni], acc[mi][ni], 0, 0, 0);
    }
    cur ^= 1;
  }

  if (!vmode) {
    // C/D layout col=l16 (gn), row=quad*4+r (gm). Q gets QSCALE.
#pragma unroll
    for (int mi = 0; mi < 4; ++mi) {
#pragma unroll
      for (int ni = 0; ni < 4; ++ni) {
        const int gmB = m0 + wm + mi * 16 + quad * 4;
        const int gn = n0 + wn + ni * 16 + l16;
        const int which = gn / DIM_C;  // 0 or 1 here
        const int rem = gn - which * DIM_C;
        const int h = rem >> 6, d = rem & 63;
        const float sc = (which == 0) ? QSCALE : 1.0f;
        const size_t base = (size_t)which * ((size_t)BH_CNT * SEQ_N * HEAD_D);
#pragma unroll
        for (int r = 0; r < 4; ++r) {
          const int gm = gmB + r;
          const int b = gm >> 11, tok = gm & 2047;
          out[base + (((size_t)(b * NUM_H + h) * SEQ_N + tok) * HEAD_D + d)] =
              (bf16_t)(acc[mi][ni][r] * sc);
        }
      }
    }
  } else {
    // swapped tile: row(quad*4+r) = W-row (d), col(l16) = token.
    const size_t base = 2ull * BH_CNT * SEQ_N * HEAD_D;
#pragma unroll
    for (int mi = 0; mi < 4; ++mi) {
      const int tok = m0 + wm + mi * 16 + l16;  // flat B*N token
      const float wvf = 1.0f - mask[tok];
      const int b = tok >> 11, tokm = tok & 2047;
#pragma unroll
      for (int ni = 0; ni < 4; ++ni) {
#pragma unroll
        for (int r = 0; r < 4; ++r) {
          const int rowg = n0 - 2 * DIM_C + wn + ni * 16 + quad * 4 + r;
          const int h = rowg >> 6, d = rowg & 63;
          out[base + (((size_t)(b * NUM_H + h) * HEAD_D + d) * SEQ_N + tokm)] =
              (bf16_t)(acc[mi][ni][r] * wvf);
        }
      }
    }
  }
}

// ---------------------------------------------------------------------------
// Proj GEMM: out = ctx @ proj_w^T + bias, f32 out. 64x64 tile (grid 768
// blocks = 3/CU), 4 waves (2x2), wave-tile 32x32. glls + swizzle + dbuf.
// ---------------------------------------------------------------------------
__global__ __launch_bounds__(256, 4) void gemm_proj_kernel(
    const bf16_t* __restrict__ A, const bf16_t* __restrict__ W,
    const float* __restrict__ bias, float* __restrict__ out) {
  __shared__ __align__(16) bf16_t As[2][64 * 32];
  __shared__ __align__(16) bf16_t Bs[2][64 * 32];

  const int tid = threadIdx.x;
  const int wave = tid >> 6, lane = tid & 63;
  const int quad = lane >> 4, l16 = lane & 15;
  const int m0 = blockIdx.y * 64, n0 = blockIdx.x * 64;
  const int wm = (wave >> 1) * 32, wn = (wave & 1) * 32;

  f32x4 acc[2][2] = {};

  const int srow = tid >> 2;                            // 0..63
  const int scol = ((tid & 3) ^ ((tid >> 3) & 3)) * 8;
  const bf16_t* gA = A + (size_t)(m0 + srow) * DIM_C + scol;
  const bf16_t* gB = W + (size_t)(n0 + srow) * DIM_C + scol;
  const int lb = wave * 512;

  auto issue = [&](int buf, int k0) {
    __builtin_amdgcn_global_load_lds(AS1(gA + k0), AS3(&As[buf][lb]), 16, 0, 0);
    __builtin_amdgcn_global_load_lds(AS1(gB + k0), AS3(&Bs[buf][lb]), 16, 0, 0);
  };

  issue(0, 0);
  int cur = 0;
  const int sw = (l16 >> 1) & 3;
  for (int step = 0; step < DIM_C / 32; ++step) {
    __syncthreads();
    if (step + 1 < DIM_C / 32) issue(cur ^ 1, (step + 1) * 32);

    bf16x8 aF[2], bF[2];
#pragma unroll
    for (int mi = 0; mi < 2; ++mi)
      aF[mi] = *reinterpret_cast<const bf16x8*>(
          &As[cur][(wm + mi * 16 + l16) * 32 + ((quad ^ sw) * 8)]);
#pragma unroll
    for (int ni = 0; ni < 2; ++ni)
      bF[ni] = *reinterpret_cast<const bf16x8*>(
          &Bs[cur][(wn + ni * 16 + l16) * 32 + ((quad ^ sw) * 8)]);
#pragma unroll
    for (int mi = 0; mi < 2; ++mi)
#pragma unroll
      for (int ni = 0; ni < 2; ++ni)
        acc[mi][ni] = __builtin_amdgcn_mfma_f32_16x16x32_bf16(aF[mi], bF[ni],
                                                              acc[mi][ni], 0, 0, 0);
    cur ^= 1;
  }

#pragma unroll
  for (int mi = 0; mi < 2; ++mi) {
#pragma unroll
    for (int ni = 0; ni < 2; ++ni) {
      const int gmB = m0 + wm + mi * 16 + quad * 4;
      const int gn = n0 + wn + ni * 16 + l16;
      const float bv = bias[gn];
#pragma unroll
      for (int r = 0; r < 4; ++r)
        out[(size_t)(gmB + r) * DIM_C + gn] = acc[mi][ni][r] + bv;
    }
  }
}

// ---------------------------------------------------------------------------
// Flash attention (unchanged from round 5): transposed scores, p=exp2(s),
// QSCALE pre-folded into Q, V premasked, l via MFMA against w=1-mask.
// Block = 64 q of one (b,h), 4 waves x 16 q, 64-key chunks, glls dbuf.
// ---------------------------------------------------------------------------
__global__ __launch_bounds__(256, 4) void attn_kernel(
    const bf16_t* __restrict__ q, const bf16_t* __restrict__ k,
    const bf16_t* __restrict__ vt, const bf16_t* __restrict__ wv,
    bf16_t* __restrict__ ctx) {
  __shared__ __align__(16) bf16_t Ks[2][64 * 64];  // swizzled [key][d]
  __shared__ __align__(16) bf16_t Vs[2][64 * 64];  // swizzled [d][key]
  __shared__ __align__(16) bf16_t Ps[4][1024];     // swizzled per-wave P

  const int tid = threadIdx.x;
  const int wave = tid >> 6, lane = tid & 63;
  const int quad = lane >> 4, l16 = lane & 15;
  const int bh = blockIdx.y;
  const int b = bh / NUM_H, h = bh - b * NUM_H;
  const int q0 = blockIdx.x * 64 + wave * 16;

  const bf16_t* qb = q + (size_t)bh * SEQ_N * HEAD_D;
  const bf16_t* kb = k + (size_t)bh * SEQ_N * HEAD_D;
  const bf16_t* vtb = vt + (size_t)bh * HEAD_D * SEQ_N;
  const bf16_t* wb = wv + (size_t)b * SEQ_N;

  bf16x8 qf[2];
#pragma unroll
  for (int ks = 0; ks < 2; ++ks)
    qf[ks] = *reinterpret_cast<const bf16x8*>(
        &qb[(size_t)(q0 + l16) * HEAD_D + ks * 32 + quad * 8]);

  f32x4 acc[4] = {};
  f32x4 acc_l = {};

  const int srow = tid >> 3;                            // 0..31, pass1 +32
  const int scol = ((tid & 7) ^ ((tid >> 3) & 7)) * 8;
  const bf16_t* gK0 = kb + (size_t)srow * HEAD_D + scol;
  const bf16_t* gK1 = kb + (size_t)(srow + 32) * HEAD_D + scol;
  const bf16_t* gV0 = vtb + (size_t)srow * SEQ_N + scol;
  const bf16_t* gV1 = vtb + (size_t)(srow + 32) * SEQ_N + scol;
  const int lb = wave * 512;

  auto issueKV = [&](int buf, int key0) {
    __builtin_amdgcn_global_load_lds(AS1(gK0 + (size_t)key0 * HEAD_D),
                                     AS3(&Ks[buf][lb]), 16, 0, 0);
    __builtin_amdgcn_global_load_lds(AS1(gK1 + (size_t)key0 * HEAD_D),
                                     AS3(&Ks[buf][lb + 2048]), 16, 0, 0);
    __builtin_amdgcn_global_load_lds(AS1(gV0 + key0), AS3(&Vs[buf][lb]), 16, 0, 0);
    __builtin_amdgcn_global_load_lds(AS1(gV1 + key0), AS3(&Vs[buf][lb + 2048]),
                                     16, 0, 0);
  };

  issueKV(0, 0);
  int cur = 0;
  const int swz = l16 & 7;
  const int psbase = wave * 1024 + l16 * 64;
  for (int key0 = 0; key0 < SEQ_N; key0 += 64) {
    __syncthreads();
    if (key0 + 64 < SEQ_N) issueKV(cur ^ 1, key0 + 64);

    f32x4 s[4];
#pragma unroll
    for (int kt = 0; kt < 4; ++kt) {
      const int row = kt * 16 + l16;
      bf16x8 kf0 = *reinterpret_cast<const bf16x8*>(
          &Ks[cur][row * 64 + ((quad ^ swz) * 8)]);
      bf16x8 kf1 = *reinterpret_cast<const bf16x8*>(
          &Ks[cur][row * 64 + (((4 + quad) ^ swz) * 8)]);
      f32x4 z = {0.0f, 0.0f, 0.0f, 0.0f};
      z = __builtin_amdgcn_mfma_f32_16x16x32_bf16(kf0, qf[0], z, 0, 0, 0);
      s[kt] = __builtin_amdgcn_mfma_f32_16x16x32_bf16(kf1, qf[1], z, 0, 0, 0);
    }

#pragma unroll
    for (int kt = 0; kt < 4; ++kt) {
      union { ushort4 u; bf16_t h4[4]; } pk;
      pk.h4[0] = (bf16_t)exp2f(s[kt][0]);
      pk.h4[1] = (bf16_t)exp2f(s[kt][1]);
      pk.h4[2] = (bf16_t)exp2f(s[kt][2]);
      pk.h4[3] = (bf16_t)exp2f(s[kt][3]);
      const int c = kt * 2 + (quad >> 1);
      *reinterpret_cast<ushort4*>(
          &Ps[0][psbase + ((c ^ swz) << 3) + ((quad & 1) << 2)]) = pk.u;
    }

    bf16x8 pf0 = *reinterpret_cast<const bf16x8*>(
        &Ps[0][psbase + ((quad ^ swz) << 3)]);
    bf16x8 pf1 = *reinterpret_cast<const bf16x8*>(
        &Ps[0][psbase + (((4 + quad) ^ swz) << 3)]);
    bf16x8 wf0 = *reinterpret_cast<const bf16x8*>(&wb[key0 + quad * 8]);
    bf16x8 wf1 = *reinterpret_cast<const bf16x8*>(&wb[key0 + 32 + quad * 8]);
    acc_l = __builtin_amdgcn_mfma_f32_16x16x32_bf16(pf0, wf0, acc_l, 0, 0, 0);
    acc_l = __builtin_amdgcn_mfma_f32_16x16x32_bf16(pf1, wf1, acc_l, 0, 0, 0);

#pragma unroll
    for (int dt = 0; dt < 4; ++dt) {
      const int row = dt * 16 + l16;
      bf16x8 vf0 = *reinterpret_cast<const bf16x8*>(
          &Vs[cur][row * 64 + ((quad ^ swz) * 8)]);
      bf16x8 vf1 = *reinterpret_cast<const bf16x8*>(
          &Vs[cur][row * 64 + (((4 + quad) ^ swz) * 8)]);
      acc[dt] = __builtin_amdgcn_mfma_f32_16x16x32_bf16(pf0, vf0, acc[dt], 0, 0, 0);
      acc[dt] = __builtin_amdgcn_mfma_f32_16x16x32_bf16(pf1, vf1, acc[dt], 0, 0, 0);
    }
    cur ^= 1;
  }

  float rl[4];
#pragma unroll
  for (int r = 0; r < 4; ++r) rl[r] = 1.0f / acc_l[r];
#pragma unroll
  for (int dt = 0; dt < 4; ++dt)
#pragma unroll
    for (int r = 0; r < 4; ++r) {
      const int tok = q0 + quad * 4 + r;
      ctx[((size_t)b * SEQ_N + tok) * DIM_C + h * HEAD_D + dt * 16 + l16] =
          (bf16_t)(acc[dt][r] * rl[r]);
    }
}

// ---------------------------------------------------------------------------
extern "C" void kernel_launch(void* const* d_in, const int* in_sizes, int n_in,
                              void* d_out, int out_size, void* d_ws,
                              size_t ws_size, hipStream_t stream) {
  const float* x = (const float*)d_in[0];       // [B,N,C] f32
  const float* mask = (const float*)d_in[1];    // [B,N]   f32
  const float* qkv_w = (const float*)d_in[2];   // [3C,C]  f32
  const float* proj_w = (const float*)d_in[3];  // [C,C]   f32
  const float* proj_b = (const float*)d_in[4];  // [C]     f32
  float* out = (float*)d_out;                   // [B,N,C] f32

  const size_t nx = (size_t)MTOK * DIM_C;
  const size_t nqw = (size_t)3 * DIM_C * DIM_C;
  const size_t npw = (size_t)DIM_C * DIM_C;
  const size_t nmask = (size_t)NUM_B * SEQ_N;
  const size_t per = (size_t)BH_CNT * SEQ_N * HEAD_D;

  bf16_t* xb = (bf16_t*)d_ws;
  bf16_t* qwb = xb + nx;
  bf16_t* pwb = qwb + nqw;
  bf16_t* wvb = pwb + npw;       // [B,N] = 1-mask
  bf16_t* qkv = wvb + nmask;     // Q(scaled),K [B,H,N,D]; V(masked) [B,H,D,N]
  bf16_t* ctx = qkv + 3 * per;   // [B,N,C]

  const int nb0 = (int)(nx / 2048), nb1 = (int)(nqw / 2048),
            nb2 = (int)(npw / 2048), nbm = (int)(nmask / 2048);

  cvt_kernel<<<nb0 + nb1 + nb2 + nbm, 256, 0, stream>>>(
      x, qkv_w, proj_w, mask, xb, qwb, pwb, wvb, nb0, nb1, nb2);
  gemm_qkv_kernel<<<dim3(3 * DIM_C / 128, MTOK / 128), 256, 0, stream>>>(
      xb, qwb, mask, qkv);
  attn_kernel<<<dim3(SEQ_N / 64, BH_CNT), 256, 0, stream>>>(
      qkv, qkv + per, qkv + 2 * per, wvb, ctx);
  gemm_proj_kernel<<<dim3(DIM_C / 64, MTOK / 64), 256, 0, stream>>>(
      ctx, pwb, proj_b, out);
}

// Round 7
// 150.508 us; speedup vs baseline: 1.1628x; 1.1628x over previous
//
#include <hip/hip_runtime.h>

typedef __bf16 bf16_t;
typedef __bf16 bf16x8 __attribute__((ext_vector_type(8)));
typedef float f32x4 __attribute__((ext_vector_type(4)));

#define NUM_B 2
#define NUM_H 12
#define SEQ_N 2048
#define DIM_C 768
#define HEAD_D 64
#define BH_CNT (NUM_B * NUM_H)
#define MTOK (NUM_B * SEQ_N)
// qk-scale 1/8 folded with log2(e) so softmax is a bare exp2
#define QSCALE 0.1803368801111137f

#define AS1(p) ((const __attribute__((address_space(1))) void*)(p))
#define AS3(p) ((__attribute__((address_space(3))) void*)(p))

// ---------------------------------------------------------------------------
// f32 -> bf16 bulk convert (x, qkv_w, proj_w); final NUM_B blocks do the
// mask scan: stable-partition tokens into src[] (visible first, masked pad),
// w'[pos] = 1/0 bf16, cnts[b*2] = cntPad64, cnts[b*2+1] = count.
// ---------------------------------------------------------------------------
__global__ __launch_bounds__(256) void cvt_scan_kernel(
    const float* __restrict__ s0, const float* __restrict__ s1,
    const float* __restrict__ s2, const float* __restrict__ msk,
    bf16_t* __restrict__ d0, bf16_t* __restrict__ d1, bf16_t* __restrict__ d2,
    int* __restrict__ src, bf16_t* __restrict__ wp, int* __restrict__ cnts,
    int nb0, int nb1, int nb2) {
  __shared__ int psum[256];
  const int blk = blockIdx.x;
  const int t = threadIdx.x;
  if (blk >= nb0 + nb1 + nb2) {
    // ---- mask scan for batch b ----
    const int b = blk - (nb0 + nb1 + nb2);
    const float* mb = msk + (size_t)b * SEQ_N;
    int vis[8], c = 0;
#pragma unroll
    for (int j = 0; j < 8; ++j) {
      vis[j] = (mb[t * 8 + j] == 0.0f) ? 1 : 0;
      c += vis[j];
    }
    psum[t] = c;
    __syncthreads();
    for (int off = 1; off < 256; off <<= 1) {
      int v = (t >= off) ? psum[t - off] : 0;
      __syncthreads();
      psum[t] += v;
      __syncthreads();
    }
    const int total = psum[255];
    int vpos = psum[t] - c;                  // visible written so far
    int mpos = total + (t * 8 - (psum[t] - c));  // masked go after count
#pragma unroll
    for (int j = 0; j < 8; ++j) {
      const int tok = t * 8 + j;
      if (vis[j]) {
        src[b * SEQ_N + vpos] = b * SEQ_N + tok;
        wp[b * SEQ_N + vpos] = (bf16_t)1.0f;
        ++vpos;
      } else {
        src[b * SEQ_N + mpos] = b * SEQ_N + tok;
        wp[b * SEQ_N + mpos] = (bf16_t)0.0f;
        ++mpos;
      }
    }
    if (t == 0) {
      cnts[b * 2] = (total + 63) & ~63;
      cnts[b * 2 + 1] = total;
    }
    return;
  }
  // ---- bulk f32 -> bf16 ----
  const float* sp;
  bf16_t* dp;
  size_t off;
  if (blk < nb0) {
    sp = s0; dp = d0; off = (size_t)blk * 2048;
  } else if (blk < nb0 + nb1) {
    sp = s1; dp = d1; off = (size_t)(blk - nb0) * 2048;
  } else {
    sp = s2; dp = d2; off = (size_t)(blk - nb0 - nb1) * 2048;
  }
  const size_t i = off + (size_t)t * 8;
  float4 f0 = *reinterpret_cast<const float4*>(&sp[i]);
  float4 f1 = *reinterpret_cast<const float4*>(&sp[i + 4]);
  union { ushort4 u; bf16_t h[4]; } p0, p1;
  p0.h[0] = (bf16_t)f0.x; p0.h[1] = (bf16_t)f0.y;
  p0.h[2] = (bf16_t)f0.z; p0.h[3] = (bf16_t)f0.w;
  p1.h[0] = (bf16_t)f1.x; p1.h[1] = (bf16_t)f1.y;
  p1.h[2] = (bf16_t)f1.z; p1.h[3] = (bf16_t)f1.w;
  *reinterpret_cast<ushort4*>(&dp[i]) = p0.u;
  *reinterpret_cast<ushort4*>(&dp[i + 4]) = p1.u;
}

// ---------------------------------------------------------------------------
// QKV GEMM (round-4 structure, 128x128 tile, glls 16B, XOR swizzle, dbuf).
// n0<768: Q for all tokens (x QSCALE), [B,H,N,D].
// 768<=n0<1536: K over COMPACTED rows (A-row = x[src[m]]), K'[B,H,pos,D].
// n0>=1536: V over COMPACTED rows, V'^T[B,H,D,pos], zeroed for pos>=count.
// K/V blocks fully beyond cntPad64 exit immediately.
// ---------------------------------------------------------------------------
__global__ __launch_bounds__(256, 3) void gemm_qkv_kernel(
    const bf16_t* __restrict__ A, const bf16_t* __restrict__ W,
    const int* __restrict__ src, const int* __restrict__ cnts,
    bf16_t* __restrict__ out) {
  __shared__ __align__(16) bf16_t As[2][128 * 32];
  __shared__ __align__(16) bf16_t Bs[2][128 * 32];

  const int tid = threadIdx.x;
  const int wave = tid >> 6, lane = tid & 63;
  const int quad = lane >> 4, l16 = lane & 15;
  const int m0 = blockIdx.y * 128, n0 = blockIdx.x * 128;
  const int wm = (wave >> 1) * 64, wn = (wave & 1) * 64;
  const bool isQ = (n0 < DIM_C);

  if (!isQ) {
    const int b = m0 >> 11;
    if ((m0 & 2047) >= cnts[b * 2]) return;  // all-pad block, never read
  }

  f32x4 acc[4][4] = {};

  const int srow = tid >> 2;                            // 0..63, pass1 +64
  const int scol = ((tid & 3) ^ ((tid >> 3) & 3)) * 8;  // swizzled col
  int ar0, ar1;
  if (isQ) {
    ar0 = m0 + srow;
    ar1 = m0 + srow + 64;
  } else {
    ar0 = src[m0 + srow];
    ar1 = src[m0 + srow + 64];
  }
  const bf16_t* gA0 = A + (size_t)ar0 * DIM_C + scol;
  const bf16_t* gA1 = A + (size_t)ar1 * DIM_C + scol;
  const bf16_t* gB0 = W + (size_t)(n0 + srow) * DIM_C + scol;
  const bf16_t* gB1 = W + (size_t)(n0 + srow + 64) * DIM_C + scol;
  const int lb = wave * 512;

  auto issue = [&](int buf, int k0) {
    __builtin_amdgcn_global_load_lds(AS1(gA0 + k0), AS3(&As[buf][lb]), 16, 0, 0);
    __builtin_amdgcn_global_load_lds(AS1(gA1 + k0), AS3(&As[buf][lb + 2048]), 16, 0, 0);
    __builtin_amdgcn_global_load_lds(AS1(gB0 + k0), AS3(&Bs[buf][lb]), 16, 0, 0);
    __builtin_amdgcn_global_load_lds(AS1(gB1 + k0), AS3(&Bs[buf][lb + 2048]), 16, 0, 0);
  };

  issue(0, 0);
  int cur = 0;
  const int sw = (l16 >> 1) & 3;
  for (int step = 0; step < DIM_C / 32; ++step) {
    __syncthreads();
    if (step + 1 < DIM_C / 32) issue(cur ^ 1, (step + 1) * 32);

    bf16x8 aF[4], bF[4];
#pragma unroll
    for (int mi = 0; mi < 4; ++mi)
      aF[mi] = *reinterpret_cast<const bf16x8*>(
          &As[cur][(wm + mi * 16 + l16) * 32 + ((quad ^ sw) * 8)]);
#pragma unroll
    for (int ni = 0; ni < 4; ++ni)
      bF[ni] = *reinterpret_cast<const bf16x8*>(
          &Bs[cur][(wn + ni * 16 + l16) * 32 + ((quad ^ sw) * 8)]);
#pragma unroll
    for (int mi = 0; mi < 4; ++mi)
#pragma unroll
      for (int ni = 0; ni < 4; ++ni)
        acc[mi][ni] = __builtin_amdgcn_mfma_f32_16x16x32_bf16(aF[mi], bF[ni],
                                                              acc[mi][ni], 0, 0, 0);
    cur ^= 1;
  }

  // epilogue: C/D layout col=l16 (gn), row=quad*4+r (gm)
  const size_t per = (size_t)BH_CNT * SEQ_N * HEAD_D;
#pragma unroll
  for (int mi = 0; mi < 4; ++mi) {
#pragma unroll
    for (int ni = 0; ni < 4; ++ni) {
      const int gmB = m0 + wm + mi * 16 + quad * 4;
      const int gn = n0 + wn + ni * 16 + l16;
      const int b = gmB >> 11;
      if (isQ) {
        const int h = gn >> 6, d = gn & 63;
#pragma unroll
        for (int r = 0; r < 4; ++r) {
          const int gm = gmB + r;
          const int tok = gm & 2047;
          out[(((size_t)((gm >> 11) * NUM_H + h) * SEQ_N + tok) * HEAD_D + d)] =
              (bf16_t)(acc[mi][ni][r] * QSCALE);
        }
      } else if (n0 < 2 * DIM_C) {  // K'
        const int rem = gn - DIM_C;
        const int h = rem >> 6, d = rem & 63;
#pragma unroll
        for (int r = 0; r < 4; ++r) {
          const int pos = (gmB + r) & 2047;
          out[per + (((size_t)(b * NUM_H + h) * SEQ_N + pos) * HEAD_D + d)] =
              (bf16_t)acc[mi][ni][r];
        }
      } else {  // V'^T, zero pad columns
        const int rem = gn - 2 * DIM_C;
        const int h = rem >> 6, d = rem & 63;
        const int pos0 = gmB & 2047;
        const int count = cnts[b * 2 + 1];
        union { ushort4 u; bf16_t h4[4]; } pk;
#pragma unroll
        for (int r = 0; r < 4; ++r)
          pk.h4[r] = (pos0 + r < count) ? (bf16_t)acc[mi][ni][r] : (bf16_t)0.0f;
        *reinterpret_cast<ushort4*>(
            &out[2 * per + (((size_t)(b * NUM_H + h) * HEAD_D + d) * SEQ_N + pos0)]) =
            pk.u;
      }
    }
  }
}

// ---------------------------------------------------------------------------
// Proj GEMM (round-4 structure): out = ctx @ proj_w^T + bias, f32 out.
// 128x128 tile, glls, swizzle, dbuf.
// ---------------------------------------------------------------------------
__global__ __launch_bounds__(256, 3) void gemm_proj_kernel(
    const bf16_t* __restrict__ A, const bf16_t* __restrict__ W,
    const float* __restrict__ bias, float* __restrict__ out) {
  __shared__ __align__(16) bf16_t As[2][128 * 32];
  __shared__ __align__(16) bf16_t Bs[2][128 * 32];

  const int tid = threadIdx.x;
  const int wave = tid >> 6, lane = tid & 63;
  const int quad = lane >> 4, l16 = lane & 15;
  const int m0 = blockIdx.y * 128, n0 = blockIdx.x * 128;
  const int wm = (wave >> 1) * 64, wn = (wave & 1) * 64;

  f32x4 acc[4][4] = {};

  const int srow = tid >> 2;
  const int scol = ((tid & 3) ^ ((tid >> 3) & 3)) * 8;
  const bf16_t* gA0 = A + (size_t)(m0 + srow) * DIM_C + scol;
  const bf16_t* gA1 = A + (size_t)(m0 + srow + 64) * DIM_C + scol;
  const bf16_t* gB0 = W + (size_t)(n0 + srow) * DIM_C + scol;
  const bf16_t* gB1 = W + (size_t)(n0 + srow + 64) * DIM_C + scol;
  const int lb = wave * 512;

  auto issue = [&](int buf, int k0) {
    __builtin_amdgcn_global_load_lds(AS1(gA0 + k0), AS3(&As[buf][lb]), 16, 0, 0);
    __builtin_amdgcn_global_load_lds(AS1(gA1 + k0), AS3(&As[buf][lb + 2048]), 16, 0, 0);
    __builtin_amdgcn_global_load_lds(AS1(gB0 + k0), AS3(&Bs[buf][lb]), 16, 0, 0);
    __builtin_amdgcn_global_load_lds(AS1(gB1 + k0), AS3(&Bs[buf][lb + 2048]), 16, 0, 0);
  };

  issue(0, 0);
  int cur = 0;
  const int sw = (l16 >> 1) & 3;
  for (int step = 0; step < DIM_C / 32; ++step) {
    __syncthreads();
    if (step + 1 < DIM_C / 32) issue(cur ^ 1, (step + 1) * 32);

    bf16x8 aF[4], bF[4];
#pragma unroll
    for (int mi = 0; mi < 4; ++mi)
      aF[mi] = *reinterpret_cast<const bf16x8*>(
          &As[cur][(wm + mi * 16 + l16) * 32 + ((quad ^ sw) * 8)]);
#pragma unroll
    for (int ni = 0; ni < 4; ++ni)
      bF[ni] = *reinterpret_cast<const bf16x8*>(
          &Bs[cur][(wn + ni * 16 + l16) * 32 + ((quad ^ sw) * 8)]);
#pragma unroll
    for (int mi = 0; mi < 4; ++mi)
#pragma unroll
      for (int ni = 0; ni < 4; ++ni)
        acc[mi][ni] = __builtin_amdgcn_mfma_f32_16x16x32_bf16(aF[mi], bF[ni],
                                                              acc[mi][ni], 0, 0, 0);
    cur ^= 1;
  }

#pragma unroll
  for (int mi = 0; mi < 4; ++mi) {
#pragma unroll
    for (int ni = 0; ni < 4; ++ni) {
      const int gmB = m0 + wm + mi * 16 + quad * 4;
      const int gn = n0 + wn + ni * 16 + l16;
      const float bv = bias[gn];
#pragma unroll
      for (int r = 0; r < 4; ++r)
        out[(size_t)(gmB + r) * DIM_C + gn] = acc[mi][ni][r] + bv;
    }
  }
}

// ---------------------------------------------------------------------------
// Flash attention over COMPACTED keys: loop bound cntPad64 (per batch),
// transposed scores, p=exp2(s) (no max), l via MFMA against w'.
// q: [B,H,N,D] (xQSCALE); k': [B,H,pos,D]; vt': [B,H,D,pos] (pad cols 0).
// ---------------------------------------------------------------------------
__global__ __launch_bounds__(256, 4) void attn_kernel(
    const bf16_t* __restrict__ q, const bf16_t* __restrict__ k,
    const bf16_t* __restrict__ vt, const bf16_t* __restrict__ wp,
    const int* __restrict__ cnts, bf16_t* __restrict__ ctx) {
  __shared__ __align__(16) bf16_t Ks[2][64 * 64];  // swizzled [key][d]
  __shared__ __align__(16) bf16_t Vs[2][64 * 64];  // swizzled [d][key]
  __shared__ __align__(16) bf16_t Ps[4][1024];     // swizzled per-wave P

  const int tid = threadIdx.x;
  const int wave = tid >> 6, lane = tid & 63;
  const int quad = lane >> 4, l16 = lane & 15;
  const int bh = blockIdx.y;
  const int b = bh / NUM_H, h = bh - b * NUM_H;
  const int q0 = blockIdx.x * 64 + wave * 16;
  const int cntPad = cnts[b * 2];

  const bf16_t* qb = q + (size_t)bh * SEQ_N * HEAD_D;
  const bf16_t* kb = k + (size_t)bh * SEQ_N * HEAD_D;
  const bf16_t* vtb = vt + (size_t)bh * HEAD_D * SEQ_N;
  const bf16_t* wb = wp + (size_t)b * SEQ_N;

  bf16x8 qf[2];
#pragma unroll
  for (int ks = 0; ks < 2; ++ks)
    qf[ks] = *reinterpret_cast<const bf16x8*>(
        &qb[(size_t)(q0 + l16) * HEAD_D + ks * 32 + quad * 8]);

  f32x4 acc[4] = {};
  f32x4 acc_l = {};

  const int srow = tid >> 3;                            // 0..31, pass1 +32
  const int scol = ((tid & 7) ^ ((tid >> 3) & 7)) * 8;
  const bf16_t* gK0 = kb + (size_t)srow * HEAD_D + scol;
  const bf16_t* gK1 = kb + (size_t)(srow + 32) * HEAD_D + scol;
  const bf16_t* gV0 = vtb + (size_t)srow * SEQ_N + scol;
  const bf16_t* gV1 = vtb + (size_t)(srow + 32) * SEQ_N + scol;
  const int lb = wave * 512;

  auto issueKV = [&](int buf, int key0) {
    __builtin_amdgcn_global_load_lds(AS1(gK0 + (size_t)key0 * HEAD_D),
                                     AS3(&Ks[buf][lb]), 16, 0, 0);
    __builtin_amdgcn_global_load_lds(AS1(gK1 + (size_t)key0 * HEAD_D),
                                     AS3(&Ks[buf][lb + 2048]), 16, 0, 0);
    __builtin_amdgcn_global_load_lds(AS1(gV0 + key0), AS3(&Vs[buf][lb]), 16, 0, 0);
    __builtin_amdgcn_global_load_lds(AS1(gV1 + key0), AS3(&Vs[buf][lb + 2048]),
                                     16, 0, 0);
  };

  issueKV(0, 0);
  int cur = 0;
  const int swz = l16 & 7;
  const int psbase = wave * 1024 + l16 * 64;
  for (int key0 = 0; key0 < cntPad; key0 += 64) {
    __syncthreads();
    if (key0 + 64 < cntPad) issueKV(cur ^ 1, key0 + 64);

    f32x4 s[4];
#pragma unroll
    for (int kt = 0; kt < 4; ++kt) {
      const int row = kt * 16 + l16;
      bf16x8 kf0 = *reinterpret_cast<const bf16x8*>(
          &Ks[cur][row * 64 + ((quad ^ swz) * 8)]);
      bf16x8 kf1 = *reinterpret_cast<const bf16x8*>(
          &Ks[cur][row * 64 + (((4 + quad) ^ swz) * 8)]);
      f32x4 z = {0.0f, 0.0f, 0.0f, 0.0f};
      z = __builtin_amdgcn_mfma_f32_16x16x32_bf16(kf0, qf[0], z, 0, 0, 0);
      s[kt] = __builtin_amdgcn_mfma_f32_16x16x32_bf16(kf1, qf[1], z, 0, 0, 0);
    }

#pragma unroll
    for (int kt = 0; kt < 4; ++kt) {
      union { ushort4 u; bf16_t h4[4]; } pk;
      pk.h4[0] = (bf16_t)exp2f(s[kt][0]);
      pk.h4[1] = (bf16_t)exp2f(s[kt][1]);
      pk.h4[2] = (bf16_t)exp2f(s[kt][2]);
      pk.h4[3] = (bf16_t)exp2f(s[kt][3]);
      const int c = kt * 2 + (quad >> 1);
      *reinterpret_cast<ushort4*>(
          &Ps[0][psbase + ((c ^ swz) << 3) + ((quad & 1) << 2)]) = pk.u;
    }

    bf16x8 pf0 = *reinterpret_cast<const bf16x8*>(
        &Ps[0][psbase + ((quad ^ swz) << 3)]);
    bf16x8 pf1 = *reinterpret_cast<const bf16x8*>(
        &Ps[0][psbase + (((4 + quad) ^ swz) << 3)]);
    bf16x8 wf0 = *reinterpret_cast<const bf16x8*>(&wb[key0 + quad * 8]);
    bf16x8 wf1 = *reinterpret_cast<const bf16x8*>(&wb[key0 + 32 + quad * 8]);
    acc_l = __builtin_amdgcn_mfma_f32_16x16x32_bf16(pf0, wf0, acc_l, 0, 0, 0);
    acc_l = __builtin_amdgcn_mfma_f32_16x16x32_bf16(pf1, wf1, acc_l, 0, 0, 0);

#pragma unroll
    for (int dt = 0; dt < 4; ++dt) {
      const int row = dt * 16 + l16;
      bf16x8 vf0 = *reinterpret_cast<const bf16x8*>(
          &Vs[cur][row * 64 + ((quad ^ swz) * 8)]);
      bf16x8 vf1 = *reinterpret_cast<const bf16x8*>(
          &Vs[cur][row * 64 + (((4 + quad) ^ swz) * 8)]);
      acc[dt] = __builtin_amdgcn_mfma_f32_16x16x32_bf16(pf0, vf0, acc[dt], 0, 0, 0);
      acc[dt] = __builtin_amdgcn_mfma_f32_16x16x32_bf16(pf1, vf1, acc[dt], 0, 0, 0);
    }
    cur ^= 1;
  }

  float rl[4];
#pragma unroll
  for (int r = 0; r < 4; ++r) rl[r] = 1.0f / acc_l[r];
#pragma unroll
  for (int dt = 0; dt < 4; ++dt)
#pragma unroll
    for (int r = 0; r < 4; ++r) {
      const int tok = q0 + quad * 4 + r;
      ctx[((size_t)b * SEQ_N + tok) * DIM_C + h * HEAD_D + dt * 16 + l16] =
          (bf16_t)(acc[dt][r] * rl[r]);
    }
}

// ---------------------------------------------------------------------------
extern "C" void kernel_launch(void* const* d_in, const int* in_sizes, int n_in,
                              void* d_out, int out_size, void* d_ws,
                              size_t ws_size, hipStream_t stream) {
  const float* x = (const float*)d_in[0];       // [B,N,C] f32
  const float* mask = (const float*)d_in[1];    // [B,N]   f32
  const float* qkv_w = (const float*)d_in[2];   // [3C,C]  f32
  const float* proj_w = (const float*)d_in[3];  // [C,C]   f32
  const float* proj_b = (const float*)d_in[4];  // [C]     f32
  float* out = (float*)d_out;                   // [B,N,C] f32

  const size_t nx = (size_t)MTOK * DIM_C;
  const size_t nqw = (size_t)3 * DIM_C * DIM_C;
  const size_t npw = (size_t)DIM_C * DIM_C;
  const size_t per = (size_t)BH_CNT * SEQ_N * HEAD_D;

  bf16_t* xb = (bf16_t*)d_ws;
  bf16_t* qwb = xb + nx;
  bf16_t* pwb = qwb + nqw;
  bf16_t* wpb = pwb + npw;            // [B,N] bf16 w' (1 visible / 0 pad)
  int* srcb = (int*)(wpb + MTOK);     // [B*N] compacted->orig token (aligned)
  int* cntsb = srcb + MTOK;           // [B*2]: cntPad64, count
  bf16_t* qkv = (bf16_t*)(cntsb + 8); // Q [B,H,N,D]; K' [B,H,pos,D]; V'^T [B,H,D,pos]
  bf16_t* ctx = qkv + 3 * per;        // [B,N,C]

  const int nb0 = (int)(nx / 2048), nb1 = (int)(nqw / 2048),
            nb2 = (int)(npw / 2048);

  cvt_scan_kernel<<<nb0 + nb1 + nb2 + NUM_B, 256, 0, stream>>>(
      x, qkv_w, proj_w, mask, xb, qwb, pwb, srcb, wpb, cntsb, nb0, nb1, nb2);
  gemm_qkv_kernel<<<dim3(3 * DIM_C / 128, MTOK / 128), 256, 0, stream>>>(
      xb, qwb, srcb, cntsb, qkv);
  attn_kernel<<<dim3(SEQ_N / 64, BH_CNT), 256, 0, stream>>>(
      qkv, qkv + per, qkv + 2 * per, wpb, cntsb, ctx);
  gemm_proj_kernel<<<dim3(DIM_C / 128, MTOK / 128), 256, 0, stream>>>(
      ctx, pwb, proj_b, out);
}